// Round 6
// baseline (3314.703 us; speedup 1.0000x reference)
//
#include <hip/hip_runtime.h>

#define NBATCH 64
#define NCH    128
#define NTYPE  6
#define NK     127
#define N1     25
#define N2     50
#define N3     100
#define NAXIS  4
#define OUTPER 400  // N3*NAXIS
#define Y2PAD  53   // 53 coprime with 32 -> conflict-free strided LDS writes

__device__ __forceinline__ float tanh_fast(float x) {
    float e = __expf(2.0f * x);                       // e^{2x}; inf/0 saturate correctly
    return 1.0f - 2.0f * __builtin_amdgcn_rcpf(e + 1.0f);
}

// broadcast lane i of v to all lanes (i must be compile-time constant via unroll)
__device__ __forceinline__ float lane_bcast(float v, int i) {
    return __int_as_float(__builtin_amdgcn_readlane(__float_as_int(v), i));
}

// coords (NB,NC,3) -> ct[(j*3+d)*NB + b]  (lane=b contiguous)
__global__ void k_transpose(const float* __restrict__ coords, float* __restrict__ ct) {
    int t = blockIdx.x * blockDim.x + threadIdx.x;
    if (t >= NBATCH * NCH * 3) return;
    int b  = t & (NBATCH - 1);
    int jd = t >> 6;
    int d  = jd % 3;
    int j  = jd / 3;
    ct[t] = coords[(b * NCH + j) * 3 + d];
}

// W3[ch][g][i] -> w3t[(ch*50+i)*100 + g]  (i-major, g contiguous for lane=g loads)
__global__ void k_wt(const float* __restrict__ W3, float* __restrict__ w3t) {
    int t = blockIdx.x * blockDim.x + threadIdx.x;   // t = (ch*N2+i)*N3 + g
    if (t >= 36 * N2 * N3) return;
    int g  = t % N3;
    int ci = t / N3;
    int i  = ci % N2;
    int ch = ci / N2;
    w3t[t] = W3[ch * (N3 * N2) + g * N2 + i];
}

// Kernel A: t1[n,a*4+f,b] = sum_k env_a[b,n,k,a] * out[b,n,k,f<4]
// wave = (n, k-slice of 8), lane = b. Weights wave-uniform -> scalar loads.
// t1buf layout [n][12][b] so atomics and k_res2 loads are lane-coalesced.
__global__ __launch_bounds__(256, 4) void k_t1(
    const float* __restrict__ ct, const int* __restrict__ types,
    const float* __restrict__ W1, const float* __restrict__ B1,
    const float* __restrict__ W2, const float* __restrict__ B2,
    const float* __restrict__ W3, const float* __restrict__ B3,
    float* __restrict__ t1buf)
{
    const int n  = blockIdx.x >> 2;
    const int qc = blockIdx.x & 3;
    const int w  = threadIdx.x >> 6;
    const int b  = threadIdx.x & 63;
    const int k0 = qc * 32 + w * 8;

    const float cx = ct[(n*3+0)*NBATCH + b];
    const float cy = ct[(n*3+1)*NBATCH + b];
    const float cz = ct[(n*3+2)*NBATCH + b];
    const int tn = __builtin_amdgcn_readfirstlane(types[n]);

    float t1a[12];
#pragma unroll
    for (int i = 0; i < 12; ++i) t1a[i] = 0.0f;

    for (int kk = 0; kk < 8; ++kk) {
        const int k = k0 + kk;
        if (k >= NK) break;
        const int j  = __builtin_amdgcn_readfirstlane((k < n) ? k : k + 1);
        const int ch = __builtin_amdgcn_readfirstlane(tn * NTYPE + types[j]);

        const float dx = cx - ct[(j*3+0)*NBATCH + b];
        const float dy = cy - ct[(j*3+1)*NBATCH + b];
        const float dz = cz - ct[(j*3+2)*NBATCH + b];
        const float d2 = dx*dx + dy*dy + dz*dz;
        const float dd = sqrtf(d2);
        const float dinv = __builtin_amdgcn_rcpf(fmaxf(dd, 1e-12f));
        const float di2 = dinv * dinv;
        const float ax = dx * di2, ay = dy * di2, az = dz * di2;

        const float* w1 = W1 + ch * N1;
        const float* b1 = B1 + ch * N1;
        float y1[N1];
#pragma unroll
        for (int o = 0; o < N1; ++o)
            y1[o] = tanh_fast(fmaf(dinv, w1[o], b1[o]));

        const float* w2 = W2 + ch * (N2 * N1);
        const float* b2 = B2 + ch * N2;
        float y2[N2];
#pragma unroll
        for (int o = 0; o < N2; ++o) y2[o] = b2[o];
#pragma unroll 5
        for (int i = 0; i < N1; ++i) {
            const float yv = y1[i];
#pragma unroll
            for (int o = 0; o < N2; ++o) y2[o] = fmaf(w2[o*N1+i], yv, y2[o]);
        }
#pragma unroll
        for (int o = 0; o < N2; ++o)
            y2[o] = tanh_fast(y2[o]) + y1[(o >= N1) ? (o - N1) : o];

        const float* w3 = W3 + ch * (N3 * N2);
        const float* b3 = B3 + ch * N3;
#pragma unroll
        for (int f = 0; f < NAXIS; ++f) {
            float z = b3[f];
#pragma unroll
            for (int i = 0; i < N2; ++i) z = fmaf(w3[f*N2+i], y2[i], z);
            const float o4 = tanh_fast(z) + y2[f];
            t1a[0*4+f] = fmaf(ax, o4, t1a[0*4+f]);
            t1a[1*4+f] = fmaf(ay, o4, t1a[1*4+f]);
            t1a[2*4+f] = fmaf(az, o4, t1a[2*4+f]);
        }
    }

    float* dst = t1buf + (n * 12) * NBATCH + b;   // [n][i][b] — lane-coalesced
#pragma unroll
    for (int i = 0; i < 12; ++i) atomicAdd(dst + i * NBATCH, t1a[i]);
}

// Kernel B: block = (n, g-half). 8 waves, ALL 127 k in one block.
// Phase1 (lane=b): wave (kk2=w>>1, h=w&1) computes y1 + y2-half for k=kb+kk2
// into LDS y2t[kk][b][53]; h==0 wave also computes t2[b,f]=env·t1 into t2s.
// Phase2 (lane=g within half): per k, lane g holds its private w3 column in
// 50 VGPRs (coalesced vector loads, L2-hot); y2[b][i] broadcast via one
// ds_read (lane=i) + v_readlane in the unrolled i-loop. Residual y2[g%50]
// equals this lane's own vy2. Output slice owned exclusively -> plain
// float4 stores, NO atomics (round-4's 410 MB WRITE_SIZE was atomic RMW).
// (512,4) NOT (512,2): every (…,2) submission killed the build container
// (suspected backend hang at 256-VGPR budget on big unrolled nests).
__global__ __launch_bounds__(512, 4) void k_res2(
    const float* __restrict__ ct, const int* __restrict__ types,
    const float* __restrict__ W1, const float* __restrict__ B1,
    const float* __restrict__ W2, const float* __restrict__ B2,
    const float* __restrict__ w3t, const float* __restrict__ B3,
    const float* __restrict__ t1buf, float* __restrict__ out)
{
    __shared__ float y2t[4 * NBATCH * Y2PAD + 16];  // 54.3 KB
    __shared__ float t2s[4 * NBATCH * NAXIS];       //  4.1 KB

    const int n    = blockIdx.x >> 1;
    const int gh   = blockIdx.x & 1;
    const int w    = threadIdx.x >> 6;
    const int lane = threadIdx.x & 63;

    // ---- phase-1 identity: lane = b, wave = (kk2, h) ----
    const int kk2 = w >> 1;
    const int h   = w & 1;
    const int tn  = __builtin_amdgcn_readfirstlane(types[n]);
    const float cx = ct[(n*3+0)*NBATCH + lane];
    const float cy = ct[(n*3+1)*NBATCH + lane];
    const float cz = ct[(n*3+2)*NBATCH + lane];

    float t1r[12];
#pragma unroll
    for (int i = 0; i < 12; ++i) t1r[i] = t1buf[(n*12 + i)*NBATCH + lane];

    // ---- phase-2 identity: lane = g - gh*50, wave w owns b in [w*8, w*8+8) ----
    const int b0 = w * 8;
    float racc[8][NAXIS];
#pragma unroll
    for (int bi = 0; bi < 8; ++bi)
#pragma unroll
        for (int f = 0; f < NAXIS; ++f) racc[bi][f] = 0.0f;

    for (int kc = 0; kc < 32; ++kc) {
        const int kb = kc * 4;
        // ================= phase 1 =================
        {
            const int k = kb + kk2;
            if (k < NK) {
                const int j  = __builtin_amdgcn_readfirstlane((k < n) ? k : k + 1);
                const int ch = __builtin_amdgcn_readfirstlane(tn * NTYPE + types[j]);
                const float dx = cx - ct[(j*3+0)*NBATCH + lane];
                const float dy = cy - ct[(j*3+1)*NBATCH + lane];
                const float dz = cz - ct[(j*3+2)*NBATCH + lane];
                const float d2 = dx*dx + dy*dy + dz*dz;
                const float dd = sqrtf(d2);
                const float dinv = __builtin_amdgcn_rcpf(fmaxf(dd, 1e-12f));
                const float di2 = dinv * dinv;
                if (h == 0) {
                    const float ax = dx * di2, ay = dy * di2, az = dz * di2;
#pragma unroll
                    for (int f = 0; f < NAXIS; ++f) {
                        const float t2f = ax*t1r[0*4+f] + ay*t1r[1*4+f] + az*t1r[2*4+f];
                        t2s[(kk2*NBATCH + lane)*NAXIS + f] = t2f;
                    }
                }
                const float* w1 = W1 + ch * N1;
                const float* b1 = B1 + ch * N1;
                float y1[N1];
#pragma unroll
                for (int o = 0; o < N1; ++o)
                    y1[o] = tanh_fast(fmaf(dinv, w1[o], b1[o]));
                const int ob = h * N1;   // 0 or 25
                const float* w2 = W2 + ch * (N2*N1) + ob * N1;
                const float* b2 = B2 + ch * N2 + ob;
#pragma unroll 5
                for (int oi = 0; oi < N1; ++oi) {
                    float z = b2[oi];
#pragma unroll
                    for (int i = 0; i < N1; ++i) z = fmaf(w2[oi*N1+i], y1[i], z);
                    y2t[(kk2*NBATCH + lane)*Y2PAD + ob + oi] = tanh_fast(z) + y1[oi];
                }
            }
        }
        __syncthreads();
        // ================= phase 2 =================
        for (int kk = 0; kk < 4; ++kk) {
            const int k = kb + kk;
            if (k >= NK) break;
            const int j  = __builtin_amdgcn_readfirstlane((k < n) ? k : k + 1);
            const int ch = __builtin_amdgcn_readfirstlane(tn * NTYPE + types[j]);

            // lane-private w3 column + bias (coalesced vector loads, L2-hot)
            const int gcol = gh * N2 + lane;       // g for this lane
            float w3c[N2];
#pragma unroll 10
            for (int i = 0; i < N2; ++i)
                w3c[i] = (lane < N2) ? w3t[(ch*N2 + i)*N3 + gcol] : 0.0f;
            const float b3v = (lane < N2) ? B3[ch*N3 + gcol] : 0.0f;

#pragma unroll 2
            for (int bi = 0; bi < 8; ++bi) {
                const int b = b0 + bi;
                const float vy2 = y2t[(kk*NBATCH + b)*Y2PAD + lane];   // lane=i
                const float4 t2v = *(const float4*)&t2s[(kk*NBATCH + b)*NAXIS];
                float z0 = b3v, z1 = 0.0f;
#pragma unroll
                for (int i = 0; i < N2; i += 2) {
                    z0 = fmaf(lane_bcast(vy2, i),     w3c[i],     z0);
                    z1 = fmaf(lane_bcast(vy2, i + 1), w3c[i + 1], z1);
                }
                const float o3 = tanh_fast(z0 + z1) + vy2;  // residual y2[g%50]=vy2
                racc[bi][0] = fmaf(o3, t2v.x, racc[bi][0]);
                racc[bi][1] = fmaf(o3, t2v.y, racc[bi][1]);
                racc[bi][2] = fmaf(o3, t2v.z, racc[bi][2]);
                racc[bi][3] = fmaf(o3, t2v.w, racc[bi][3]);
            }
        }
        __syncthreads();
    }

    if (lane < N2) {
        const int g = gh * N2 + lane;
#pragma unroll
        for (int bi = 0; bi < 8; ++bi) {
            const int b = b0 + bi;
            float4 st;
            st.x = racc[bi][0]; st.y = racc[bi][1];
            st.z = racc[bi][2]; st.w = racc[bi][3];
            *(float4*)&out[(b*NCH + n)*OUTPER + g*NAXIS] = st;   // exclusive slice
        }
    }
}

extern "C" void kernel_launch(void* const* d_in, const int* in_sizes, int n_in,
                              void* d_out, int out_size, void* d_ws, size_t ws_size,
                              hipStream_t stream) {
    const float* coords = (const float*)d_in[0];
    const int*   types  = (const int*)d_in[1];
    const float* W1 = (const float*)d_in[2];
    const float* B1 = (const float*)d_in[3];
    const float* W2 = (const float*)d_in[4];
    const float* B2 = (const float*)d_in[5];
    const float* W3 = (const float*)d_in[6];
    const float* B3 = (const float*)d_in[7];
    float* out = (float*)d_out;

    float* t1buf = (float*)d_ws;                          // 128*12*64   = 98304 f
    float* ct    = t1buf + NCH * 12 * NBATCH;             // 64*128*3    = 24576 f
    float* w3t   = ct + NBATCH * NCH * 3;                 // 36*50*100   = 180000 f

    hipMemsetAsync(t1buf, 0, (size_t)NCH * 12 * NBATCH * sizeof(float), stream);

    k_transpose<<<(NBATCH*NCH*3 + 255)/256, 256, 0, stream>>>(coords, ct);
    k_wt<<<(36*N2*N3 + 255)/256, 256, 0, stream>>>(W3, w3t);
    k_t1 <<<NCH*4, 256, 0, stream>>>(ct, types, W1,B1,W2,B2,W3,B3, t1buf);
    k_res2<<<NCH*2, 512, 0, stream>>>(ct, types, W1,B1,W2,B2, w3t, B3, t1buf, out);
}

// Round 8
// 1560.816 us; speedup vs baseline: 2.1237x; 2.1237x over previous
//
#include <hip/hip_runtime.h>

#define NBATCH 64
#define NCH    128
#define NTYPE  6
#define NK     127
#define N1     25
#define N2     50
#define N3     100
#define NAXIS  4
#define OUTPER 400  // N3*NAXIS
#define Y2PAD  54   // stride 54 dwords: 54%32=22, gcd(22,32)=2 -> 2-way alias = free

// ---------- repetition macros: straight-line code, literal indices ONLY ----------
// (clang refuses to fully unroll trip-25/50 loops; dynamic reg-array indices then
//  demote arrays to scratch -> the 8+ GB spill traffic seen in rounds 1/4/6)
#define R7(M)  M(0) M(1) M(2) M(3) M(4) M(5) M(6)
#define R12(M) M(0) M(1) M(2) M(3) M(4) M(5) M(6) M(7) M(8) M(9) M(10) M(11)
#define R25(M) M(0) M(1) M(2) M(3) M(4) M(5) M(6) M(7) M(8) M(9) M(10) M(11) M(12) \
               M(13) M(14) M(15) M(16) M(17) M(18) M(19) M(20) M(21) M(22) M(23) M(24)
#define R25A(M,a) M(a,0) M(a,1) M(a,2) M(a,3) M(a,4) M(a,5) M(a,6) M(a,7) M(a,8) M(a,9) \
               M(a,10) M(a,11) M(a,12) M(a,13) M(a,14) M(a,15) M(a,16) M(a,17) M(a,18) \
               M(a,19) M(a,20) M(a,21) M(a,22) M(a,23) M(a,24)
#define R50(M) R25(M) M(25) M(26) M(27) M(28) M(29) M(30) M(31) M(32) M(33) M(34) \
               M(35) M(36) M(37) M(38) M(39) M(40) M(41) M(42) M(43) M(44) M(45) \
               M(46) M(47) M(48) M(49)

__device__ __forceinline__ float tanh_fast(float x) {
    float e = __expf(2.0f * x);                       // e^{2x}; inf/0 saturate correctly
    return 1.0f - 2.0f * __builtin_amdgcn_rcpf(e + 1.0f);
}

// coords (NB,NC,3) -> ct[(j*3+d)*NB + b]  (lane=b contiguous)
__global__ void k_transpose(const float* __restrict__ coords, float* __restrict__ ct) {
    int t = blockIdx.x * blockDim.x + threadIdx.x;
    if (t >= NBATCH * NCH * 3) return;
    int b  = t & (NBATCH - 1);
    int jd = t >> 6;
    int d  = jd % 3;
    int j  = jd / 3;
    ct[t] = coords[(b * NCH + j) * 3 + d];
}

// Kernel A: t1[n, a*4+f, b] = sum_k env_a * out4_f.  wave=(n, 8-k slice), lane=b.
// Weights wave-uniform -> s_load. All nests macro-flattened; live set ~60 floats.
__global__ __launch_bounds__(256, 4) void k_mlp(
    const float* __restrict__ ct, const int* __restrict__ types,
    const float* __restrict__ W1, const float* __restrict__ B1,
    const float* __restrict__ W2, const float* __restrict__ B2,
    const float* __restrict__ W3, const float* __restrict__ B3,
    float* __restrict__ t1buf)
{
    const int n  = blockIdx.x >> 2;
    const int qc = blockIdx.x & 3;
    const int w  = threadIdx.x >> 6;
    const int b  = threadIdx.x & 63;
    const int k0 = qc * 32 + w * 8;

    const float cx = ct[(n*3+0)*NBATCH + b];
    const float cy = ct[(n*3+1)*NBATCH + b];
    const float cz = ct[(n*3+2)*NBATCH + b];
    const int tn = __builtin_amdgcn_readfirstlane(types[n]);

    float t1a[12];
#define TIN(i) t1a[i] = 0.0f;
    R12(TIN)
#undef TIN

    for (int kk = 0; kk < 8; ++kk) {
        const int k = k0 + kk;
        if (k >= NK) break;
        const int j  = __builtin_amdgcn_readfirstlane((k < n) ? k : k + 1);
        const int ch = __builtin_amdgcn_readfirstlane(tn * NTYPE + types[j]);

        const float dx = cx - ct[(j*3+0)*NBATCH + b];
        const float dy = cy - ct[(j*3+1)*NBATCH + b];
        const float dz = cz - ct[(j*3+2)*NBATCH + b];
        const float d2 = dx*dx + dy*dy + dz*dz;
        const float dd = sqrtf(d2);
        const float dinv = __builtin_amdgcn_rcpf(fmaxf(dd, 1e-12f));
        const float di2 = dinv * dinv;
        const float ax = dx * di2, ay = dy * di2, az = dz * di2;

        const float* w1r = W1 + ch * N1;
        const float* b1r = B1 + ch * N1;
        float y1[N1];
#define L1S(o) y1[o] = tanh_fast(fmaf(dinv, w1r[o], b1r[o]));
        R25(L1S)
#undef L1S

        const float* w2r = W2 + ch * (N2 * N1);
        const float* b2r = B2 + ch * N2;
        const float* w3r = W3 + ch * (N3 * N2);
        float zf[4];
        zf[0] = B3[ch*N3+0]; zf[1] = B3[ch*N3+1];
        zf[2] = B3[ch*N3+2]; zf[3] = B3[ch*N3+3];
        float r[4];
#define MLP2I(o,i) z = fmaf(w2r[(o)*N1+(i)], y1[i], z);
#define MLP2(o) { float z = b2r[o]; R25A(MLP2I,o) \
        float y2o = tanh_fast(z) + y1[(o)%N1]; \
        if ((o) < 4) r[(o)&3] = y2o; \
        zf[0] = fmaf(w3r[0*N2+(o)], y2o, zf[0]); \
        zf[1] = fmaf(w3r[1*N2+(o)], y2o, zf[1]); \
        zf[2] = fmaf(w3r[2*N2+(o)], y2o, zf[2]); \
        zf[3] = fmaf(w3r[3*N2+(o)], y2o, zf[3]); }
        R50(MLP2)
#undef MLP2
#undef MLP2I

#define O4F(f) { float o4 = tanh_fast(zf[f]) + r[f]; \
        t1a[0+(f)] = fmaf(ax, o4, t1a[0+(f)]); \
        t1a[4+(f)] = fmaf(ay, o4, t1a[4+(f)]); \
        t1a[8+(f)] = fmaf(az, o4, t1a[8+(f)]); }
        O4F(0) O4F(1) O4F(2) O4F(3)
#undef O4F
    }

    float* dst = t1buf + (n * 12) * NBATCH + b;   // [n][i][b] lane-coalesced
#define TAT(i) atomicAdd(dst + (i) * NBATCH, t1a[i]);
    R12(TAT)
#undef TAT
}

// Kernel B: block = (n, g-half), 512 thr. Phase1 (lane=b): wave-pairs stage
// y2 for 4 k's into LDS (stride 54 = 2-way alias, free). Phase2 (lane=b):
// wave w owns 7 g's of its half; w3 rows are wave-uniform s_loads (SMEM pipe),
// y2 read from LDS in 25-reg chunks, residual y2[g%50] one extra ds_read.
// Exclusive output slices -> plain float4 stores, no atomics.
// Live ~100 VGPR < 128 cap of (512,4). No (..,2) bounds (container-killer).
__global__ __launch_bounds__(512, 4) void k_res2(
    const float* __restrict__ ct, const int* __restrict__ types,
    const float* __restrict__ W1, const float* __restrict__ B1,
    const float* __restrict__ W2, const float* __restrict__ B2,
    const float* __restrict__ W3, const float* __restrict__ B3,
    const float* __restrict__ t1buf, float* __restrict__ out)
{
    __shared__ float y2t[4 * NBATCH * Y2PAD];      // 55296 B

    const int n    = blockIdx.x >> 1;
    const int gh   = blockIdx.x & 1;
    const int w    = threadIdx.x >> 6;
    const int lane = threadIdx.x & 63;            // = b in both phases
    const int kk2  = w >> 1;                      // phase-1 k of chunk
    const int h    = w & 1;                       // phase-1 y2 half
    const int g0   = w * 7;                       // phase-2 g-slice (7 per wave)

    const int tn = __builtin_amdgcn_readfirstlane(types[n]);
    const float cx = ct[(n*3+0)*NBATCH + lane];
    const float cy = ct[(n*3+1)*NBATCH + lane];
    const float cz = ct[(n*3+2)*NBATCH + lane];

    float t1r[12];
#define T1L(i) t1r[i] = t1buf[(n*12 + (i))*NBATCH + lane];
    R12(T1L)
#undef T1L

    float racc[7][4];
#define RIN(gi) racc[gi][0]=0.f; racc[gi][1]=0.f; racc[gi][2]=0.f; racc[gi][3]=0.f;
    R7(RIN)
#undef RIN

    for (int kc = 0; kc < 32; ++kc) {
        const int kb = kc * 4;
        // ================= phase 1: stage y2 for 4 k's =================
        {
            const int k = kb + kk2;
            if (k < NK) {
                const int j  = __builtin_amdgcn_readfirstlane((k < n) ? k : k + 1);
                const int ch = __builtin_amdgcn_readfirstlane(tn * NTYPE + types[j]);
                const float dx = cx - ct[(j*3+0)*NBATCH + lane];
                const float dy = cy - ct[(j*3+1)*NBATCH + lane];
                const float dz = cz - ct[(j*3+2)*NBATCH + lane];
                const float d2 = dx*dx + dy*dy + dz*dz;
                const float dd = sqrtf(d2);
                const float dinv = __builtin_amdgcn_rcpf(fmaxf(dd, 1e-12f));

                const float* w1r = W1 + ch * N1;
                const float* b1r = B1 + ch * N1;
                float y1[N1];
#define L1S(o) y1[o] = tanh_fast(fmaf(dinv, w1r[o], b1r[o]));
                R25(L1S)
#undef L1S
                const int ob = h * N1;            // 0 or 25
                const float* w2h = W2 + ch * (N2*N1) + ob * N1;
                const float* b2h = B2 + ch * N2 + ob;
                const int y2o = (kk2*NBATCH + lane)*Y2PAD + ob;
#define P1I(oi,i) z = fmaf(w2h[(oi)*N1+(i)], y1[i], z);
#define P1S(oi) { float z = b2h[oi]; R25A(P1I,oi) \
                  y2t[y2o + (oi)] = tanh_fast(z) + y1[oi]; }
                R25(P1S)
#undef P1S
#undef P1I
            }
        }
        __syncthreads();
        // ================= phase 2: layer 3 + contractions =================
        for (int kk = 0; kk < 4; ++kk) {
            const int k = kb + kk;
            if (k >= NK) break;
            const int j  = __builtin_amdgcn_readfirstlane((k < n) ? k : k + 1);
            const int ch = __builtin_amdgcn_readfirstlane(tn * NTYPE + types[j]);

            const float dx = cx - ct[(j*3+0)*NBATCH + lane];
            const float dy = cy - ct[(j*3+1)*NBATCH + lane];
            const float dz = cz - ct[(j*3+2)*NBATCH + lane];
            const float d2 = dx*dx + dy*dy + dz*dz;
            const float dd = sqrtf(d2);
            const float dinv = __builtin_amdgcn_rcpf(fmaxf(dd, 1e-12f));
            const float di2 = dinv * dinv;
            const float ax = dx * di2, ay = dy * di2, az = dz * di2;

            float t2v[4];
#define T2C(f) t2v[f] = ax*t1r[f] + ay*t1r[4+(f)] + az*t1r[8+(f)];
            T2C(0) T2C(1) T2C(2) T2C(3)
#undef T2C

            const float* w3b = W3 + ch * (N3*N2) + (gh*N2) * N2;  // rows of this half
            const float* b3b = B3 + ch * N3 + gh * N2;
            const int yo = (kk*NBATCH + lane)*Y2PAD;

            int   gg[7];
            float z[7];
#define PGI(gi) { int gl = g0 + (gi); gg[gi] = (gl < N2) ? gl : (N2-1); \
                  z[gi] = b3b[gg[gi]]; }
            R7(PGI)
#undef PGI

            float y2v[N1];
#define LD0(i) y2v[i] = y2t[yo + (i)];
            R25(LD0)
#undef LD0
#define PH0(gi,i) z[gi] = fmaf(w3b[gg[gi]*N2 + (i)], y2v[i], z[gi]);
#define PH0G(gi) R25A(PH0,gi)
            R7(PH0G)
#undef PH0G
#undef PH0
#define LD1(i) y2v[i] = y2t[yo + N1 + (i)];
            R25(LD1)
#undef LD1
#define PH1(gi,i) z[gi] = fmaf(w3b[gg[gi]*N2 + N1 + (i)], y2v[i], z[gi]);
#define PH1G(gi) R25A(PH1,gi)
            R7(PH1G)
#undef PH1G
#undef PH1

#define PFIN(gi) { float rv = y2t[yo + gg[gi]]; \
                   float o3 = tanh_fast(z[gi]) + rv; \
                   racc[gi][0] = fmaf(o3, t2v[0], racc[gi][0]); \
                   racc[gi][1] = fmaf(o3, t2v[1], racc[gi][1]); \
                   racc[gi][2] = fmaf(o3, t2v[2], racc[gi][2]); \
                   racc[gi][3] = fmaf(o3, t2v[3], racc[gi][3]); }
            R7(PFIN)
#undef PFIN
        }
        __syncthreads();
    }

#define PST(gi) if (g0 + (gi) < N2) { \
        float4 st; st.x = racc[gi][0]; st.y = racc[gi][1]; \
        st.z = racc[gi][2]; st.w = racc[gi][3]; \
        *(float4*)&out[(lane*NCH + n)*OUTPER + (gh*N2 + g0 + (gi))*NAXIS] = st; }
    R7(PST)
#undef PST
}

extern "C" void kernel_launch(void* const* d_in, const int* in_sizes, int n_in,
                              void* d_out, int out_size, void* d_ws, size_t ws_size,
                              hipStream_t stream) {
    const float* coords = (const float*)d_in[0];
    const int*   types  = (const int*)d_in[1];
    const float* W1 = (const float*)d_in[2];
    const float* B1 = (const float*)d_in[3];
    const float* W2 = (const float*)d_in[4];
    const float* B2 = (const float*)d_in[5];
    const float* W3 = (const float*)d_in[6];
    const float* B3 = (const float*)d_in[7];
    float* out = (float*)d_out;

    float* t1buf = (float*)d_ws;                          // 128*12*64 floats
    float* ct    = t1buf + NCH * 12 * NBATCH;             // 64*128*3 floats

    hipMemsetAsync(t1buf, 0, (size_t)NCH * 12 * NBATCH * sizeof(float), stream);

    k_transpose<<<(NBATCH*NCH*3 + 255)/256, 256, 0, stream>>>(coords, ct);
    k_mlp <<<NCH*4, 256, 0, stream>>>(ct, types, W1,B1,W2,B2,W3,B3, t1buf);
    k_res2<<<NCH*2, 512, 0, stream>>>(ct, types, W1,B1,W2,B2,W3,B3, t1buf, out);
}

// Round 9
// 1054.006 us; speedup vs baseline: 3.1449x; 1.4808x over previous
//
#include <hip/hip_runtime.h>

#define NBATCH 64
#define NCH    128
#define NTYPE  6
#define NK     127
#define N1     25
#define N2     50
#define N3     100
#define NAXIS  4
#define OUTPER 400  // N3*NAXIS
#define Y2PAD  54   // stride 54 dwords: 54%32=22, gcd(22,32)=2 -> 2-way alias = free

// ---------- repetition macros: straight-line code, literal indices ONLY ----------
#define R7(M)  M(0) M(1) M(2) M(3) M(4) M(5) M(6)
#define R10(M) M(0) M(1) M(2) M(3) M(4) M(5) M(6) M(7) M(8) M(9)
#define R10A(M,a) M(a,0) M(a,1) M(a,2) M(a,3) M(a,4) M(a,5) M(a,6) M(a,7) M(a,8) M(a,9)
#define R12(M) R10(M) M(10) M(11)
#define R25(M) M(0) M(1) M(2) M(3) M(4) M(5) M(6) M(7) M(8) M(9) M(10) M(11) M(12) \
               M(13) M(14) M(15) M(16) M(17) M(18) M(19) M(20) M(21) M(22) M(23) M(24)
#define R25A(M,a) M(a,0) M(a,1) M(a,2) M(a,3) M(a,4) M(a,5) M(a,6) M(a,7) M(a,8) M(a,9) \
               M(a,10) M(a,11) M(a,12) M(a,13) M(a,14) M(a,15) M(a,16) M(a,17) M(a,18) \
               M(a,19) M(a,20) M(a,21) M(a,22) M(a,23) M(a,24)
#define R50(M) R25(M) M(25) M(26) M(27) M(28) M(29) M(30) M(31) M(32) M(33) M(34) \
               M(35) M(36) M(37) M(38) M(39) M(40) M(41) M(42) M(43) M(44) M(45) \
               M(46) M(47) M(48) M(49)

__device__ __forceinline__ float tanh_fast(float x) {
    float e = __expf(2.0f * x);                       // e^{2x}; inf/0 saturate correctly
    return 1.0f - 2.0f * __builtin_amdgcn_rcpf(e + 1.0f);
}

// coords (NB,NC,3) -> ct[(j*3+d)*NB + b]  (lane=b contiguous)
__global__ void k_transpose(const float* __restrict__ coords, float* __restrict__ ct) {
    int t = blockIdx.x * blockDim.x + threadIdx.x;
    if (t >= NBATCH * NCH * 3) return;
    int b  = t & (NBATCH - 1);
    int jd = t >> 6;
    int d  = jd % 3;
    int j  = jd / 3;
    ct[t] = coords[(b * NCH + j) * 3 + d];
}

// single-thread counting sort of k=0..126 keyed by types[j(k)], via LDS-staged types.
// Sorted order groups k's by channel -> W2/W3 scalar loads become K$-hot
// (round-8 FETCH 360 MB == every per-k W3 re-read went to HBM at ~900 cyc).
__device__ __forceinline__ void sort_k_by_type(
    const int* __restrict__ types, int n, int* tysh, int* ks, int* bins, int tid, int nthr)
{
    for (int t = tid; t < NCH; t += nthr) tysh[t] = types[t];
    __syncthreads();
    if (tid == 0) {
        for (int t = 0; t < NTYPE; ++t) bins[t] = 0;
        for (int k = 0; k < NK; ++k) { int j = (k < n) ? k : k + 1; bins[tysh[j]]++; }
        int off = 0;
        for (int t = 0; t < NTYPE; ++t) { int c = bins[t]; bins[t] = off; off += c; }
        for (int k = 0; k < NK; ++k) { int j = (k < n) ? k : k + 1; ks[bins[tysh[j]]++] = k; }
    }
    __syncthreads();
}

// Kernel A: t1[n, a*4+f, b] = sum_k env_a * out4_f.  wave=(n, 8-k slice), lane=b.
// k's processed in type-sorted order (K$ reuse of W2/W3 across consecutive k).
__global__ __launch_bounds__(256, 4) void k_mlp(
    const float* __restrict__ ct, const int* __restrict__ types,
    const float* __restrict__ W1, const float* __restrict__ B1,
    const float* __restrict__ W2, const float* __restrict__ B2,
    const float* __restrict__ W3, const float* __restrict__ B3,
    float* __restrict__ t1buf)
{
    __shared__ int ks[NK];
    __shared__ int tysh[NCH];
    __shared__ int bins[NTYPE];

    const int n  = blockIdx.x >> 2;
    const int qc = blockIdx.x & 3;
    const int w  = threadIdx.x >> 6;
    const int b  = threadIdx.x & 63;
    const int k0 = qc * 32 + w * 8;

    sort_k_by_type(types, n, tysh, ks, bins, threadIdx.x, 256);

    const float cx = ct[(n*3+0)*NBATCH + b];
    const float cy = ct[(n*3+1)*NBATCH + b];
    const float cz = ct[(n*3+2)*NBATCH + b];
    const int tn = __builtin_amdgcn_readfirstlane(tysh[n]);

    float t1a[12];
#define TIN(i) t1a[i] = 0.0f;
    R12(TIN)
#undef TIN

    for (int kk = 0; kk < 8; ++kk) {
        const int kidx = k0 + kk;
        if (kidx >= NK) break;
        const int sk = __builtin_amdgcn_readfirstlane(ks[kidx]);
        const int j  = (sk < n) ? sk : sk + 1;
        const int ch = __builtin_amdgcn_readfirstlane(tn * NTYPE + tysh[j]);

        const float dx = cx - ct[(j*3+0)*NBATCH + b];
        const float dy = cy - ct[(j*3+1)*NBATCH + b];
        const float dz = cz - ct[(j*3+2)*NBATCH + b];
        const float d2 = dx*dx + dy*dy + dz*dz;
        const float dd = sqrtf(d2);
        const float dinv = __builtin_amdgcn_rcpf(fmaxf(dd, 1e-12f));
        const float di2 = dinv * dinv;
        const float ax = dx * di2, ay = dy * di2, az = dz * di2;

        const float* w1r = W1 + ch * N1;
        const float* b1r = B1 + ch * N1;
        float y1[N1];
#define L1S(o) y1[o] = tanh_fast(fmaf(dinv, w1r[o], b1r[o]));
        R25(L1S)
#undef L1S

        const float* w2r = W2 + ch * (N2 * N1);
        const float* b2r = B2 + ch * N2;
        const float* w3r = W3 + ch * (N3 * N2);
        float zf[4];
        zf[0] = B3[ch*N3+0]; zf[1] = B3[ch*N3+1];
        zf[2] = B3[ch*N3+2]; zf[3] = B3[ch*N3+3];
        float r[4];
#define MLP2I(o,i) z = fmaf(w2r[(o)*N1+(i)], y1[i], z);
#define MLP2(o) { float z = b2r[o]; R25A(MLP2I,o) \
        float y2o = tanh_fast(z) + y1[(o)%N1]; \
        if ((o) < 4) r[(o)&3] = y2o; \
        zf[0] = fmaf(w3r[0*N2+(o)], y2o, zf[0]); \
        zf[1] = fmaf(w3r[1*N2+(o)], y2o, zf[1]); \
        zf[2] = fmaf(w3r[2*N2+(o)], y2o, zf[2]); \
        zf[3] = fmaf(w3r[3*N2+(o)], y2o, zf[3]); }
        R50(MLP2)
#undef MLP2
#undef MLP2I

#define O4F(f) { float o4 = tanh_fast(zf[f]) + r[f]; \
        t1a[0+(f)] = fmaf(ax, o4, t1a[0+(f)]); \
        t1a[4+(f)] = fmaf(ay, o4, t1a[4+(f)]); \
        t1a[8+(f)] = fmaf(az, o4, t1a[8+(f)]); }
        O4F(0) O4F(1) O4F(2) O4F(3)
#undef O4F
    }

    float* dst = t1buf + (n * 12) * NBATCH + b;   // [n][i][b] lane-coalesced
#define TAT(i) atomicAdd(dst + (i) * NBATCH, t1a[i]);
    R12(TAT)
#undef TAT
}

// Kernel B: block = (n, g-half), 512 thr, k's in type-sorted order.
// Phase1 (lane=b): wave-pairs stage y2 for 4 k's into LDS; h==0 waves also
// compute t2[b][f] from t1s (LDS) into t2s. Phase2 (lane=b): wave w owns 7 g's;
// w3 rows are wave-uniform s_loads (g0 readfirstlane'd — round 8 wasn't!),
// K$-hot thanks to sorting; y2 in 10-wide LDS chunks keeps live set ~55 VGPR
// (under the 64-VGPR allocation the compiler insists on -> no spills).
// Exclusive output slices -> plain float4 stores, no atomics.
__global__ __launch_bounds__(512, 4) void k_res2(
    const float* __restrict__ ct, const int* __restrict__ types,
    const float* __restrict__ W1, const float* __restrict__ B1,
    const float* __restrict__ W2, const float* __restrict__ B2,
    const float* __restrict__ W3, const float* __restrict__ B3,
    const float* __restrict__ t1buf, float* __restrict__ out)
{
    __shared__ float y2t[4 * NBATCH * Y2PAD];      // 55296 B
    __shared__ float t2s[4 * NBATCH * NAXIS];      //  4096 B
    __shared__ float t1s[12 * NBATCH];             //  3072 B
    __shared__ int   ks[NK];
    __shared__ int   tysh[NCH];
    __shared__ int   bins[NTYPE];

    const int n    = blockIdx.x >> 1;
    const int gh   = blockIdx.x & 1;
    const int w    = threadIdx.x >> 6;
    const int lane = threadIdx.x & 63;            // = b in both phases
    const int kk2  = w >> 1;                      // phase-1 k of chunk
    const int h    = w & 1;                       // phase-1 y2 half

    // stage t1 into LDS (768 floats)
    {
        int idx = threadIdx.x;
        t1s[idx >= 768 ? 0 : idx] = t1buf[n*768 + (idx >= 768 ? 0 : idx)];
        if (threadIdx.x < 256) t1s[512 + threadIdx.x] = t1buf[n*768 + 512 + threadIdx.x];
    }
    sort_k_by_type(types, n, tysh, ks, bins, threadIdx.x, 512);

    const int tn = __builtin_amdgcn_readfirstlane(tysh[n]);
    const float cx = ct[(n*3+0)*NBATCH + lane];
    const float cy = ct[(n*3+1)*NBATCH + lane];
    const float cz = ct[(n*3+2)*NBATCH + lane];

    const int g0 = __builtin_amdgcn_readfirstlane(w * 7);   // wave-uniform!
    int gg[7];
#define GGI(gi) gg[gi] = ((g0 + (gi)) < N2) ? (g0 + (gi)) : (N2 - 1);
    R7(GGI)
#undef GGI

    float racc[7][4];
#define RIN(gi) racc[gi][0]=0.f; racc[gi][1]=0.f; racc[gi][2]=0.f; racc[gi][3]=0.f;
    R7(RIN)
#undef RIN

    for (int kc = 0; kc < 32; ++kc) {
        const int kb = kc * 4;
        // ================= phase 1: stage y2 (+t2) for 4 sorted k's =================
        {
            const int kidx = kb + kk2;
            if (kidx < NK) {
                const int sk = __builtin_amdgcn_readfirstlane(ks[kidx]);
                const int j  = (sk < n) ? sk : sk + 1;
                const int ch = __builtin_amdgcn_readfirstlane(tn * NTYPE + tysh[j]);
                const float dx = cx - ct[(j*3+0)*NBATCH + lane];
                const float dy = cy - ct[(j*3+1)*NBATCH + lane];
                const float dz = cz - ct[(j*3+2)*NBATCH + lane];
                const float d2 = dx*dx + dy*dy + dz*dz;
                const float dd = sqrtf(d2);
                const float dinv = __builtin_amdgcn_rcpf(fmaxf(dd, 1e-12f));

                if (h == 0) {
                    const float di2 = dinv * dinv;
                    const float ax = dx * di2, ay = dy * di2, az = dz * di2;
#define T2W(f) t2s[(kk2*NBATCH + lane)*NAXIS + (f)] = \
                    ax*t1s[(0+(f))*NBATCH+lane] + ay*t1s[(4+(f))*NBATCH+lane] \
                  + az*t1s[(8+(f))*NBATCH+lane];
                    T2W(0) T2W(1) T2W(2) T2W(3)
#undef T2W
                }

                const float* w1r = W1 + ch * N1;
                const float* b1r = B1 + ch * N1;
                float y1[N1];
#define L1S(o) y1[o] = tanh_fast(fmaf(dinv, w1r[o], b1r[o]));
                R25(L1S)
#undef L1S
                const int ob = h * N1;            // 0 or 25
                const float* w2h = W2 + ch * (N2*N1) + ob * N1;
                const float* b2h = B2 + ch * N2 + ob;
                const int y2o = (kk2*NBATCH + lane)*Y2PAD + ob;
#define P1I(oi,i) z = fmaf(w2h[(oi)*N1+(i)], y1[i], z);
#define P1S(oi) { float z = b2h[oi]; R25A(P1I,oi) \
                  y2t[y2o + (oi)] = tanh_fast(z) + y1[oi]; }
                R25(P1S)
#undef P1S
#undef P1I
            }
        }
        __syncthreads();
        // ================= phase 2: layer 3 + contractions =================
        for (int kk = 0; kk < 4; ++kk) {
            const int kidx = kb + kk;
            if (kidx >= NK) break;
            const int sk = __builtin_amdgcn_readfirstlane(ks[kidx]);
            const int j  = (sk < n) ? sk : sk + 1;
            const int ch = __builtin_amdgcn_readfirstlane(tn * NTYPE + tysh[j]);

            const float* w3b = W3 + ch * (N3*N2) + (gh*N2) * N2;
            const float* b3b = B3 + ch * N3 + gh * N2;
            const int yo = (kk*NBATCH + lane)*Y2PAD;

            float z[7];
#define ZIN(gi) z[gi] = b3b[gg[gi]];
            R7(ZIN)
#undef ZIN
            for (int ic = 0; ic < 5; ++ic) {       // 5 chunks of 10 -> live set small
                const int io = ic * 10;
                float y2v[10];
#define LDY(i) y2v[i] = y2t[yo + io + (i)];
                R10(LDY)
#undef LDY
#define FMA1(gi,i) z[gi] = fmaf(w3b[gg[gi]*N2 + io + (i)], y2v[i], z[gi]);
#define FMAG(gi) R10A(FMA1,gi)
                R7(FMAG)
#undef FMAG
#undef FMA1
            }
            const float4 t2v = *(const float4*)&t2s[(kk*NBATCH + lane)*NAXIS];
#define PFIN(gi) { float rv = y2t[yo + gg[gi]]; \
                   float o3 = tanh_fast(z[gi]) + rv; \
                   racc[gi][0] = fmaf(o3, t2v.x, racc[gi][0]); \
                   racc[gi][1] = fmaf(o3, t2v.y, racc[gi][1]); \
                   racc[gi][2] = fmaf(o3, t2v.z, racc[gi][2]); \
                   racc[gi][3] = fmaf(o3, t2v.w, racc[gi][3]); }
            R7(PFIN)
#undef PFIN
        }
        __syncthreads();
    }

#define PST(gi) if (g0 + (gi) < N2) { \
        float4 st; st.x = racc[gi][0]; st.y = racc[gi][1]; \
        st.z = racc[gi][2]; st.w = racc[gi][3]; \
        *(float4*)&out[(lane*NCH + n)*OUTPER + (gh*N2 + g0 + (gi))*NAXIS] = st; }
    R7(PST)
#undef PST
}

extern "C" void kernel_launch(void* const* d_in, const int* in_sizes, int n_in,
                              void* d_out, int out_size, void* d_ws, size_t ws_size,
                              hipStream_t stream) {
    const float* coords = (const float*)d_in[0];
    const int*   types  = (const int*)d_in[1];
    const float* W1 = (const float*)d_in[2];
    const float* B1 = (const float*)d_in[3];
    const float* W2 = (const float*)d_in[4];
    const float* B2 = (const float*)d_in[5];
    const float* W3 = (const float*)d_in[6];
    const float* B3 = (const float*)d_in[7];
    float* out = (float*)d_out;

    float* t1buf = (float*)d_ws;                          // 128*12*64 floats
    float* ct    = t1buf + NCH * 12 * NBATCH;             // 64*128*3 floats

    hipMemsetAsync(t1buf, 0, (size_t)NCH * 12 * NBATCH * sizeof(float), stream);

    k_transpose<<<(NBATCH*NCH*3 + 255)/256, 256, 0, stream>>>(coords, ct);
    k_mlp <<<NCH*4, 256, 0, stream>>>(ct, types, W1,B1,W2,B2,W3,B3, t1buf);
    k_res2<<<NCH*2, 512, 0, stream>>>(ct, types, W1,B1,W2,B2,W3,B3, t1buf, out);
}